// Round 1
// baseline (583.430 us; speedup 1.0000x reference)
//
#include <hip/hip_runtime.h>

// GCNConv: out = D^-1/2 (A+I) D^-1/2 X W + b
// N=100000, E=1600000, Din=Dout=128, all fp32 (edge_index int32).
//
// Pipeline (all on `stream`, graph-capture safe):
//  1. k_init    : deg=1 (self loop), cnt=0
//  2. k_count   : atomic deg[col]+=w, cnt[col]+=1        (2 atomics/edge, L2-hot)
//  3. k_rsqrt   : deg -> dis = rsqrt(deg)
//  4. scan x3   : exclusive prefix sum of cnt -> rowptr (CSR by target), cursor copy
//  5. k_gemm    : h = x @ W    (fp32 vector GEMM, LDS-tiled 64x128, 4x8 microtile)
//  6. k_scatter : bucket edges: srow[pos]=row, snorm[pos]=dis[row]*w
//  7. k_gather  : 1 wave/node, 64 lanes x float2, out = b + dis[n]*(dis[n]*h[n] + sum snorm*h[srow])
//
// No fp32 scatter atomics on the 12.8M-element output (would be ~205M atomics);
// gather-side CSR accumulation keeps output writes coalesced and atomic-free.

#define ELEMS_PER_SCAN_BLOCK 2048  // 256 threads * 8

__global__ void k_init(float* deg, int* cnt, int M /*N+1*/) {
    int i = blockIdx.x * blockDim.x + threadIdx.x;
    if (i < M) {
        cnt[i] = 0;
        if (i < M - 1) deg[i] = 1.0f;  // self-loop weight
    }
}

__global__ void k_count(const int* __restrict__ col, const float* __restrict__ wgt,
                        float* deg, int* cnt, int E) {
    int e = blockIdx.x * blockDim.x + threadIdx.x;
    if (e < E) {
        int c = col[e];
        atomicAdd(&cnt[c], 1);
        atomicAdd(&deg[c], wgt[e]);
    }
}

__global__ void k_rsqrt(float* deg, int N) {
    int i = blockIdx.x * blockDim.x + threadIdx.x;
    if (i < N) {
        float d = deg[i];
        deg[i] = (d > 0.0f) ? rsqrtf(d) : 0.0f;  // deg>=1 always, guard mirrors ref
    }
}

__device__ inline int wave_incl_scan(int x, int lane) {
    #pragma unroll
    for (int d = 1; d < 64; d <<= 1) {
        int y = __shfl_up(x, d, 64);
        if (lane >= d) x += y;
    }
    return x;
}

// Block-level exclusive scan of 2048 ints; writes per-block exclusive-scanned
// values to out and block total to bsum.
__global__ void k_scan1(const int* __restrict__ in, int* __restrict__ out,
                        int* __restrict__ bsum, int M) {
    __shared__ int wsum[4];
    __shared__ int woff[4];
    int t = threadIdx.x, lane = t & 63, wid = t >> 6;
    int base = blockIdx.x * ELEMS_PER_SCAN_BLOCK + t * 8;
    int v[8];
    #pragma unroll
    for (int i = 0; i < 8; ++i) v[i] = (base + i < M) ? in[base + i] : 0;
    int run = 0;
    #pragma unroll
    for (int i = 0; i < 8; ++i) { int x = v[i]; v[i] = run; run += x; }
    int incl = wave_incl_scan(run, lane);
    int excl = incl - run;
    if (lane == 63) wsum[wid] = incl;
    __syncthreads();
    if (t == 0) {
        int r = 0;
        #pragma unroll
        for (int w = 0; w < 4; ++w) { int s = wsum[w]; woff[w] = r; r += s; }
        bsum[blockIdx.x] = r;
    }
    __syncthreads();
    int off = woff[wid] + excl;
    #pragma unroll
    for (int i = 0; i < 8; ++i)
        if (base + i < M) out[base + i] = v[i] + off;
}

// Single-block exclusive scan of NB (<=256) block sums.
__global__ void k_scan2(const int* __restrict__ bsum, int* __restrict__ boff, int NB) {
    __shared__ int wsum[4];
    __shared__ int woff[4];
    int t = threadIdx.x, lane = t & 63, wid = t >> 6;
    int x = (t < NB) ? bsum[t] : 0;
    int incl = wave_incl_scan(x, lane);
    int excl = incl - x;
    if (lane == 63) wsum[wid] = incl;
    __syncthreads();
    if (t == 0) {
        int r = 0;
        #pragma unroll
        for (int w = 0; w < 4; ++w) { int s = wsum[w]; woff[w] = r; r += s; }
    }
    __syncthreads();
    if (t < NB) boff[t] = woff[wid] + excl;
}

__global__ void k_scan3(int* __restrict__ rowptr, int* __restrict__ cursor,
                        const int* __restrict__ boff, int M) {
    int t = threadIdx.x;
    int base = blockIdx.x * ELEMS_PER_SCAN_BLOCK + t * 8;
    int off = boff[blockIdx.x];
    #pragma unroll
    for (int i = 0; i < 8; ++i) {
        int idx = base + i;
        if (idx < M) {
            int v = rowptr[idx] + off;
            rowptr[idx] = v;
            if (idx < M - 1) cursor[idx] = v;  // mutable copy for scatter
        }
    }
}

// h = x @ W. Block: 64 rows x 128 cols, 256 threads, 4x8 microtile, K-chunks of 32.
__global__ __launch_bounds__(256) void k_gemm(const float* __restrict__ x,
                                              const float* __restrict__ W,
                                              float* __restrict__ h, int N) {
    __shared__ float Xs[64][33];   // +1 pad: breaks bank aliasing on reads
    __shared__ float Ws[32][128];
    int t = threadIdx.x;
    int row0 = blockIdx.x * 64;
    int tc = t & 15;   // 8-col group
    int tr = t >> 4;   // 4-row group
    float acc[4][8];
    #pragma unroll
    for (int i = 0; i < 4; ++i)
        #pragma unroll
        for (int j = 0; j < 8; ++j) acc[i][j] = 0.0f;

    for (int k0 = 0; k0 < 128; k0 += 32) {
        // stage X chunk: 64 rows x 32 k
        #pragma unroll
        for (int rr = 0; rr < 64; rr += 32) {
            int r = rr + (t >> 3);
            int c = (t & 7) * 4;
            int gr = row0 + r;
            float4 v = make_float4(0.f, 0.f, 0.f, 0.f);
            if (gr < N) v = *(const float4*)(x + (size_t)gr * 128 + k0 + c);
            Xs[r][c] = v.x; Xs[r][c + 1] = v.y; Xs[r][c + 2] = v.z; Xs[r][c + 3] = v.w;
        }
        // stage W chunk: 32 k x 128 cols
        #pragma unroll
        for (int rr = 0; rr < 32; rr += 8) {
            int r = rr + (t >> 5);
            int c = (t & 31) * 4;
            *(float4*)&Ws[r][c] = *(const float4*)(W + (size_t)(k0 + r) * 128 + c);
        }
        __syncthreads();
        #pragma unroll
        for (int k = 0; k < 32; ++k) {
            float av[4];
            #pragma unroll
            for (int i = 0; i < 4; ++i) av[i] = Xs[4 * tr + i][k];
            float4 b0 = *(const float4*)&Ws[k][8 * tc];
            float4 b1 = *(const float4*)&Ws[k][8 * tc + 4];
            float bv[8] = {b0.x, b0.y, b0.z, b0.w, b1.x, b1.y, b1.z, b1.w};
            #pragma unroll
            for (int i = 0; i < 4; ++i)
                #pragma unroll
                for (int j = 0; j < 8; ++j) acc[i][j] += av[i] * bv[j];
        }
        __syncthreads();
    }
    #pragma unroll
    for (int i = 0; i < 4; ++i) {
        int gr = row0 + 4 * tr + i;
        if (gr < N) {
            float4 o0 = make_float4(acc[i][0], acc[i][1], acc[i][2], acc[i][3]);
            float4 o1 = make_float4(acc[i][4], acc[i][5], acc[i][6], acc[i][7]);
            *(float4*)(h + (size_t)gr * 128 + 8 * tc) = o0;
            *(float4*)(h + (size_t)gr * 128 + 8 * tc + 4) = o1;
        }
    }
}

__global__ void k_scatter(const int* __restrict__ row, const int* __restrict__ col,
                          const float* __restrict__ wgt, const float* __restrict__ dis,
                          int* cursor, int* __restrict__ srow, float* __restrict__ snorm,
                          int E) {
    int e = blockIdx.x * blockDim.x + threadIdx.x;
    if (e < E) {
        int r = row[e], c = col[e];
        float a = dis[r] * wgt[e];
        int pos = atomicAdd(&cursor[c], 1);
        srow[pos] = r;
        snorm[pos] = a;
    }
}

// One wave (64 lanes) per node; lane handles 2 feature columns.
__global__ void k_gather(const float* __restrict__ h, const float* __restrict__ dis,
                         const int* __restrict__ rowptr, const int* __restrict__ srow,
                         const float* __restrict__ snorm, const float* __restrict__ bias,
                         float* __restrict__ out, int N) {
    int gid = blockIdx.x * blockDim.x + threadIdx.x;
    int node = gid >> 6;
    int lane = gid & 63;
    if (node >= N) return;
    int c0 = lane * 2;
    float dn = dis[node];
    float2 hv = *(const float2*)(h + (size_t)node * 128 + c0);
    float2 acc;
    acc.x = dn * hv.x;   // self loop: dis[n]*1.0 coefficient
    acc.y = dn * hv.y;
    int jb = rowptr[node], je = rowptr[node + 1];
    for (int j = jb; j < je; ++j) {
        int r = srow[j];
        float a = snorm[j];
        float2 hv2 = *(const float2*)(h + (size_t)r * 128 + c0);
        acc.x += a * hv2.x;
        acc.y += a * hv2.y;
    }
    float2 bv = *(const float2*)(bias + c0);
    float2 o;
    o.x = bv.x + dn * acc.x;
    o.y = bv.y + dn * acc.y;
    *(float2*)(out + (size_t)node * 128 + c0) = o;
}

extern "C" void kernel_launch(void* const* d_in, const int* in_sizes, int n_in,
                              void* d_out, int out_size, void* d_ws, size_t ws_size,
                              hipStream_t stream) {
    const float* x     = (const float*)d_in[0];
    const int*   eidx  = (const int*)d_in[1];   // [2,E] int32 (JAX x64 disabled)
    const float* eattr = (const float*)d_in[2];
    const float* W     = (const float*)d_in[3];
    const float* bias  = (const float*)d_in[4];
    int N = in_sizes[0] / 128;
    int E = in_sizes[2];
    const int* row = eidx;
    const int* col = eidx + E;

    // workspace carve (256B-aligned): ~66 MB total
    char* p = (char*)d_ws;
    auto carve = [&](size_t bytes) {
        char* q = p;
        p += (bytes + 255) & ~(size_t)255;
        return q;
    };
    float* h      = (float*)carve((size_t)N * 128 * sizeof(float));
    float* deg    = (float*)carve((size_t)N * sizeof(float));        // -> dis in place
    int*   cnt    = (int*)carve((size_t)(N + 1) * sizeof(int));
    int*   rowptr = (int*)carve((size_t)(N + 1) * sizeof(int));
    int*   cursor = (int*)carve((size_t)N * sizeof(int));
    int*   bsum   = (int*)carve(256 * sizeof(int));
    int*   boff   = (int*)carve(256 * sizeof(int));
    int*   srow   = (int*)carve((size_t)E * sizeof(int));
    float* snorm  = (float*)carve((size_t)E * sizeof(float));

    int M = N + 1;
    int NB = (M + ELEMS_PER_SCAN_BLOCK - 1) / ELEMS_PER_SCAN_BLOCK;  // 49 for N=100k

    k_init<<<(M + 255) / 256, 256, 0, stream>>>(deg, cnt, M);
    k_count<<<(E + 255) / 256, 256, 0, stream>>>(col, eattr, deg, cnt, E);
    k_rsqrt<<<(N + 255) / 256, 256, 0, stream>>>(deg, N);
    k_scan1<<<NB, 256, 0, stream>>>(cnt, rowptr, bsum, M);
    k_scan2<<<1, 256, 0, stream>>>(bsum, boff, NB);
    k_scan3<<<NB, 256, 0, stream>>>(rowptr, cursor, boff, M);
    k_gemm<<<(N + 63) / 64, 256, 0, stream>>>(x, W, h, N);
    k_scatter<<<(E + 255) / 256, 256, 0, stream>>>(row, col, eattr, deg, cursor, srow, snorm, E);
    {
        size_t threads = (size_t)N * 64;
        int blocks = (int)((threads + 255) / 256);
        k_gather<<<blocks, 256, 0, stream>>>(h, deg, rowptr, srow, snorm, bias, (float*)d_out, N);
    }
}

// Round 2
// 430.220 us; speedup vs baseline: 1.3561x; 1.3561x over previous
//
#include <hip/hip_runtime.h>

// GCNConv: out = D^-1/2 (A+I) D^-1/2 X W + b
// N=100000, E=1600000, Din=Dout=128; x/W/b fp32, edge_index int32, out fp32.
//
// R1: h kept in bf16 (halves gather traffic; threshold is bf16-grade 3.5e-2),
//     GEMM via mfma_f32_16x16x32_bf16, gather unroll-4 + scalarized edge loads,
//     (srow,snorm) interleaved as int2.
//
// Pipeline: init -> count(atomics) -> rsqrt -> scan x3 -> wprep(W transpose->bf16)
//           -> gemm(MFMA, h bf16) -> scatter(CSR bucket) -> gather(1 wave/node).

#define ELEMS_PER_SCAN_BLOCK 2048  // 256 threads * 8

typedef __attribute__((ext_vector_type(8))) short short8;   // 8 bf16 = 4 VGPR
typedef __attribute__((ext_vector_type(4))) float f32x4;

__device__ inline unsigned short f2bf(float f) {  // fp32 -> bf16 RNE
    unsigned u = __float_as_uint(f);
    u += 0x7fffu + ((u >> 16) & 1u);
    return (unsigned short)(u >> 16);
}

__global__ void k_init(float* deg, int* cnt, int M /*N+1*/) {
    int i = blockIdx.x * blockDim.x + threadIdx.x;
    if (i < M) {
        cnt[i] = 0;
        if (i < M - 1) deg[i] = 1.0f;  // self-loop weight
    }
}

__global__ void k_count(const int* __restrict__ col, const float* __restrict__ wgt,
                        float* deg, int* cnt, int E) {
    int e = blockIdx.x * blockDim.x + threadIdx.x;
    if (e < E) {
        int c = col[e];
        atomicAdd(&cnt[c], 1);
        atomicAdd(&deg[c], wgt[e]);
    }
}

__global__ void k_rsqrt(float* deg, int N) {
    int i = blockIdx.x * blockDim.x + threadIdx.x;
    if (i < N) {
        float d = deg[i];
        deg[i] = (d > 0.0f) ? rsqrtf(d) : 0.0f;
    }
}

__device__ inline int wave_incl_scan(int x, int lane) {
    #pragma unroll
    for (int d = 1; d < 64; d <<= 1) {
        int y = __shfl_up(x, d, 64);
        if (lane >= d) x += y;
    }
    return x;
}

__global__ void k_scan1(const int* __restrict__ in, int* __restrict__ out,
                        int* __restrict__ bsum, int M) {
    __shared__ int wsum[4];
    __shared__ int woff[4];
    int t = threadIdx.x, lane = t & 63, wid = t >> 6;
    int base = blockIdx.x * ELEMS_PER_SCAN_BLOCK + t * 8;
    int v[8];
    #pragma unroll
    for (int i = 0; i < 8; ++i) v[i] = (base + i < M) ? in[base + i] : 0;
    int run = 0;
    #pragma unroll
    for (int i = 0; i < 8; ++i) { int x = v[i]; v[i] = run; run += x; }
    int incl = wave_incl_scan(run, lane);
    int excl = incl - run;
    if (lane == 63) wsum[wid] = incl;
    __syncthreads();
    if (t == 0) {
        int r = 0;
        #pragma unroll
        for (int w = 0; w < 4; ++w) { int s = wsum[w]; woff[w] = r; r += s; }
        bsum[blockIdx.x] = r;
    }
    __syncthreads();
    int off = woff[wid] + excl;
    #pragma unroll
    for (int i = 0; i < 8; ++i)
        if (base + i < M) out[base + i] = v[i] + off;
}

__global__ void k_scan2(const int* __restrict__ bsum, int* __restrict__ boff, int NB) {
    __shared__ int wsum[4];
    __shared__ int woff[4];
    int t = threadIdx.x, lane = t & 63, wid = t >> 6;
    int x = (t < NB) ? bsum[t] : 0;
    int incl = wave_incl_scan(x, lane);
    int excl = incl - x;
    if (lane == 63) wsum[wid] = incl;
    __syncthreads();
    if (t == 0) {
        int r = 0;
        #pragma unroll
        for (int w = 0; w < 4; ++w) { int s = wsum[w]; woff[w] = r; r += s; }
    }
    __syncthreads();
    if (t < NB) boff[t] = woff[wid] + excl;
}

__global__ void k_scan3(int* __restrict__ rowptr, int* __restrict__ cursor,
                        const int* __restrict__ boff, int M) {
    int t = threadIdx.x;
    int base = blockIdx.x * ELEMS_PER_SCAN_BLOCK + t * 8;
    int off = boff[blockIdx.x];
    #pragma unroll
    for (int i = 0; i < 8; ++i) {
        int idx = base + i;
        if (idx < M) {
            int v = rowptr[idx] + off;
            rowptr[idx] = v;
            if (idx < M - 1) cursor[idx] = v;
        }
    }
}

// Transpose + convert W[k][n] fp32 -> Wtg[n][k] bf16 (one-time, 64KB)
__global__ void k_wprep(const float* __restrict__ W, unsigned short* __restrict__ Wtg) {
    int n = blockIdx.x;      // 128 blocks
    int k = threadIdx.x;     // 128 threads
    Wtg[n * 128 + k] = f2bf(W[k * 128 + n]);
}

// h = x @ W in bf16 MFMA. Block: 64 rows x 128 cols, 4 waves, each wave 16 rows.
// A-frag: A[m=lane&15][k=(lane>>4)*8+j]; B-frag: B[k=(lane>>4)*8+j][n=lane&15];
// C/D: col=lane&15, row=(lane>>4)*4+reg.  (learn_hip m89-verified layouts)
__global__ __launch_bounds__(256) void k_gemm(const float* __restrict__ x,
                                              const unsigned short* __restrict__ Wtg,
                                              unsigned short* __restrict__ h, int N) {
    __shared__ short Xs[64][136];   // 64 rows x 128 k bf16, +8 pad (2-way banks: free)
    __shared__ short Ws[128][136];  // Wt[n][k] bf16
    int t = threadIdx.x;
    int lane = t & 63, wid = t >> 6;
    int row0 = blockIdx.x * 64;

    // stage X tile: thread t -> row t>>2, k-segment (t&3)*32 (32 floats -> bf16)
    {
        int r = t >> 2;
        int kseg = (t & 3) * 32;
        int gr = row0 + r;
        const float4* src = (const float4*)(x + (size_t)gr * 128 + kseg);
        #pragma unroll
        for (int i = 0; i < 4; ++i) {
            float4 v0 = make_float4(0.f, 0.f, 0.f, 0.f), v1 = v0;
            if (gr < N) { v0 = src[2 * i]; v1 = src[2 * i + 1]; }
            short8 p;
            p[0] = (short)f2bf(v0.x); p[1] = (short)f2bf(v0.y);
            p[2] = (short)f2bf(v0.z); p[3] = (short)f2bf(v0.w);
            p[4] = (short)f2bf(v1.x); p[5] = (short)f2bf(v1.y);
            p[6] = (short)f2bf(v1.z); p[7] = (short)f2bf(v1.w);
            *(short8*)&Xs[r][kseg + 8 * i] = p;
        }
    }
    // stage Wt: thread t -> n = t>>1, k-segment (t&1)*64
    {
        int n = t >> 1;
        int seg = (t & 1) * 64;
        const short* wsrc = (const short*)Wtg + n * 128 + seg;
        #pragma unroll
        for (int i = 0; i < 8; ++i)
            *(short8*)&Ws[n][seg + 8 * i] = *(const short8*)(wsrc + 8 * i);
    }
    __syncthreads();

    int q = lane >> 4;       // quad 0..3
    int m = lane & 15;
    f32x4 acc[8];
    #pragma unroll
    for (int tde = 0; tde < 8; ++tde) acc[tde] = (f32x4){0.f, 0.f, 0.f, 0.f};

    #pragma unroll
    for (int kc = 0; kc < 128; kc += 32) {
        short8 af = *(const short8*)&Xs[wid * 16 + m][kc + q * 8];
        #pragma unroll
        for (int tde = 0; tde < 8; ++tde) {
            short8 bf = *(const short8*)&Ws[tde * 16 + m][kc + q * 8];
            acc[tde] = __builtin_amdgcn_mfma_f32_16x16x32_bf16(af, bf, acc[tde], 0, 0, 0);
        }
    }

    // store: h[row0 + wid*16 + q*4 + r][tde*16 + m] bf16
    #pragma unroll
    for (int r = 0; r < 4; ++r) {
        int grow = row0 + wid * 16 + q * 4 + r;
        if (grow < N) {
            #pragma unroll
            for (int tde = 0; tde < 8; ++tde)
                h[(size_t)grow * 128 + tde * 16 + m] = f2bf(acc[tde][r]);
        }
    }
}

__global__ void k_scatter(const int* __restrict__ row, const int* __restrict__ col,
                          const float* __restrict__ wgt, const float* __restrict__ dis,
                          int* cursor, int2* __restrict__ spack, int E) {
    int e = blockIdx.x * blockDim.x + threadIdx.x;
    if (e < E) {
        int r = row[e], c = col[e];
        float a = dis[r] * wgt[e];
        int pos = atomicAdd(&cursor[c], 1);
        spack[pos] = make_int2(r, __float_as_int(a));
    }
}

// One wave per node; lane handles 2 feature cols (bf16x2 = 4B/lane loads of h).
__global__ void k_gather(const unsigned int* __restrict__ hb /*bf16 pairs*/,
                         const float* __restrict__ dis, const int* __restrict__ rowptr,
                         const int2* __restrict__ spack, const float* __restrict__ bias,
                         float* __restrict__ out, int N) {
    int gid = blockIdx.x * blockDim.x + threadIdx.x;
    int node = gid >> 6;
    int lane = gid & 63;
    if (node >= N) return;
    node = __builtin_amdgcn_readfirstlane(node);  // force wave-uniform -> s_loads

    float dn = dis[node];
    unsigned u = hb[(size_t)node * 64 + lane];
    float2 acc;
    acc.x = dn * __uint_as_float(u << 16);
    acc.y = dn * __uint_as_float(u & 0xffff0000u);

    int jb = rowptr[node], je = rowptr[node + 1];
    int j = jb;
    for (; j + 4 <= je; j += 4) {
        int2 p0 = spack[j], p1 = spack[j + 1], p2 = spack[j + 2], p3 = spack[j + 3];
        unsigned u0 = hb[(size_t)p0.x * 64 + lane];
        unsigned u1 = hb[(size_t)p1.x * 64 + lane];
        unsigned u2 = hb[(size_t)p2.x * 64 + lane];
        unsigned u3 = hb[(size_t)p3.x * 64 + lane];
        float a0 = __int_as_float(p0.y), a1 = __int_as_float(p1.y);
        float a2 = __int_as_float(p2.y), a3 = __int_as_float(p3.y);
        acc.x = fmaf(a0, __uint_as_float(u0 << 16), acc.x);
        acc.y = fmaf(a0, __uint_as_float(u0 & 0xffff0000u), acc.y);
        acc.x = fmaf(a1, __uint_as_float(u1 << 16), acc.x);
        acc.y = fmaf(a1, __uint_as_float(u1 & 0xffff0000u), acc.y);
        acc.x = fmaf(a2, __uint_as_float(u2 << 16), acc.x);
        acc.y = fmaf(a2, __uint_as_float(u2 & 0xffff0000u), acc.y);
        acc.x = fmaf(a3, __uint_as_float(u3 << 16), acc.x);
        acc.y = fmaf(a3, __uint_as_float(u3 & 0xffff0000u), acc.y);
    }
    for (; j < je; ++j) {
        int2 p = spack[j];
        unsigned uu = hb[(size_t)p.x * 64 + lane];
        float a = __int_as_float(p.y);
        acc.x = fmaf(a, __uint_as_float(uu << 16), acc.x);
        acc.y = fmaf(a, __uint_as_float(uu & 0xffff0000u), acc.y);
    }

    int c0 = lane * 2;
    float2 bv = *(const float2*)(bias + c0);
    float2 o;
    o.x = bv.x + dn * acc.x;
    o.y = bv.y + dn * acc.y;
    *(float2*)(out + (size_t)node * 128 + c0) = o;
}

extern "C" void kernel_launch(void* const* d_in, const int* in_sizes, int n_in,
                              void* d_out, int out_size, void* d_ws, size_t ws_size,
                              hipStream_t stream) {
    const float* x     = (const float*)d_in[0];
    const int*   eidx  = (const int*)d_in[1];   // [2,E] int32
    const float* eattr = (const float*)d_in[2];
    const float* W     = (const float*)d_in[3];
    const float* bias  = (const float*)d_in[4];
    int N = in_sizes[0] / 128;
    int E = in_sizes[2];
    const int* row = eidx;
    const int* col = eidx + E;

    char* p = (char*)d_ws;
    auto carve = [&](size_t bytes) {
        char* q = p;
        p += (bytes + 255) & ~(size_t)255;
        return q;
    };
    unsigned short* h   = (unsigned short*)carve((size_t)N * 128 * sizeof(unsigned short));
    unsigned short* Wtg = (unsigned short*)carve(128 * 128 * sizeof(unsigned short));
    float* deg    = (float*)carve((size_t)N * sizeof(float));   // -> dis in place
    int*   cnt    = (int*)carve((size_t)(N + 1) * sizeof(int));
    int*   rowptr = (int*)carve((size_t)(N + 1) * sizeof(int));
    int*   cursor = (int*)carve((size_t)N * sizeof(int));
    int*   bsum   = (int*)carve(256 * sizeof(int));
    int*   boff   = (int*)carve(256 * sizeof(int));
    int2*  spack  = (int2*)carve((size_t)E * sizeof(int2));

    int M = N + 1;
    int NB = (M + ELEMS_PER_SCAN_BLOCK - 1) / ELEMS_PER_SCAN_BLOCK;

    k_init<<<(M + 255) / 256, 256, 0, stream>>>(deg, cnt, M);
    k_count<<<(E + 255) / 256, 256, 0, stream>>>(col, eattr, deg, cnt, E);
    k_rsqrt<<<(N + 255) / 256, 256, 0, stream>>>(deg, N);
    k_scan1<<<NB, 256, 0, stream>>>(cnt, rowptr, bsum, M);
    k_scan2<<<1, 256, 0, stream>>>(bsum, boff, NB);
    k_scan3<<<NB, 256, 0, stream>>>(rowptr, cursor, boff, M);
    k_wprep<<<128, 128, 0, stream>>>(W, Wtg);
    k_gemm<<<(N + 63) / 64, 256, 0, stream>>>(x, Wtg, h, N);
    k_scatter<<<(E + 255) / 256, 256, 0, stream>>>(row, col, eattr, deg, cursor, spack, E);
    {
        size_t threads = (size_t)N * 64;
        int blocks = (int)((threads + 255) / 256);
        k_gather<<<blocks, 256, 0, stream>>>((const unsigned int*)h, deg, rowptr, spack,
                                             bias, (float*)d_out, N);
    }
}

// Round 3
// 314.273 us; speedup vs baseline: 1.8564x; 1.3689x over previous
//
#include <hip/hip_runtime.h>

// GCNConv: out = D^-1/2 (A+I) D^-1/2 X W + b
// N=100000, E=1600000, Din=Dout=128; x/W/b fp32, edge_index int32, out fp32.
//
// R2: single-atomic-per-edge bucketing.
//   pass1: p = atomicAdd(cnt[col])  -> tmp16[e] = p   (the ONLY atomic pass)
//   scan : rowptr = exscan(cnt)
//   pass2: spack[rowptr[col]+tmp16[e]] = (row, w)     (no atomics)
//   degsum: deg[n] = 1 + sum_bucket(w); dis = rsqrt   (no atomics)
//   gemm : h = x@W in bf16 MFMA (h stored bf16: halves gather traffic)
//   gather: out = b + dis[n]*(dis[n]*h[n] + sum dis[row]*w*h[row]), 1 wave/node.

#define ELEMS_PER_SCAN_BLOCK 2048  // 256 threads * 8

typedef __attribute__((ext_vector_type(8))) short short8;   // 8 bf16 = 4 VGPR
typedef __attribute__((ext_vector_type(4))) float f32x4;

__device__ inline unsigned short f2bf(float f) {  // fp32 -> bf16 RNE
    unsigned u = __float_as_uint(f);
    u += 0x7fffu + ((u >> 16) & 1u);
    return (unsigned short)(u >> 16);
}

// ---- pass1: histogram atomic; return value = local offset within bucket ----
__global__ void k_pass1(const int* __restrict__ col, int* cnt,
                        unsigned short* __restrict__ tmp16, int E) {
    int e = blockIdx.x * blockDim.x + threadIdx.x;
    if (e < E) {
        int c = col[e];
        int p = atomicAdd(&cnt[c], 1);
        tmp16[e] = (unsigned short)p;   // max degree << 65536
    }
}

// ---- scan (3 kernels) ----
__device__ inline int wave_incl_scan(int x, int lane) {
    #pragma unroll
    for (int d = 1; d < 64; d <<= 1) {
        int y = __shfl_up(x, d, 64);
        if (lane >= d) x += y;
    }
    return x;
}

__global__ void k_scan1(const int* __restrict__ in, int* __restrict__ out,
                        int* __restrict__ bsum, int M) {
    __shared__ int wsum[4];
    __shared__ int woff[4];
    int t = threadIdx.x, lane = t & 63, wid = t >> 6;
    int base = blockIdx.x * ELEMS_PER_SCAN_BLOCK + t * 8;
    int v[8];
    #pragma unroll
    for (int i = 0; i < 8; ++i) v[i] = (base + i < M) ? in[base + i] : 0;
    int run = 0;
    #pragma unroll
    for (int i = 0; i < 8; ++i) { int x = v[i]; v[i] = run; run += x; }
    int incl = wave_incl_scan(run, lane);
    int excl = incl - run;
    if (lane == 63) wsum[wid] = incl;
    __syncthreads();
    if (t == 0) {
        int r = 0;
        #pragma unroll
        for (int w = 0; w < 4; ++w) { int s = wsum[w]; woff[w] = r; r += s; }
        bsum[blockIdx.x] = r;
    }
    __syncthreads();
    int off = woff[wid] + excl;
    #pragma unroll
    for (int i = 0; i < 8; ++i)
        if (base + i < M) out[base + i] = v[i] + off;
}

__global__ void k_scan2(const int* __restrict__ bsum, int* __restrict__ boff, int NB) {
    __shared__ int wsum[4];
    __shared__ int woff[4];
    int t = threadIdx.x, lane = t & 63, wid = t >> 6;
    int x = (t < NB) ? bsum[t] : 0;
    int incl = wave_incl_scan(x, lane);
    int excl = incl - x;
    if (lane == 63) wsum[wid] = incl;
    __syncthreads();
    if (t == 0) {
        int r = 0;
        #pragma unroll
        for (int w = 0; w < 4; ++w) { int s = wsum[w]; woff[w] = r; r += s; }
    }
    __syncthreads();
    if (t < NB) boff[t] = woff[wid] + excl;
}

__global__ void k_scan3(int* __restrict__ rowptr, const int* __restrict__ boff, int M) {
    int t = threadIdx.x;
    int base = blockIdx.x * ELEMS_PER_SCAN_BLOCK + t * 8;
    int off = boff[blockIdx.x];
    #pragma unroll
    for (int i = 0; i < 8; ++i) {
        int idx = base + i;
        if (idx < M) rowptr[idx] += off;
    }
}

// ---- pass2: deterministic placement, no atomics ----
__global__ void k_pass2(const int* __restrict__ row, const int* __restrict__ col,
                        const float* __restrict__ wgt, const int* __restrict__ rowptr,
                        const unsigned short* __restrict__ tmp16,
                        int2* __restrict__ spack, int E) {
    int e = blockIdx.x * blockDim.x + threadIdx.x;
    if (e < E) {
        int c = col[e];
        int pos = rowptr[c] + (int)tmp16[e];
        spack[pos] = make_int2(row[e], __float_as_int(wgt[e]));
    }
}

// ---- degsum: deg[n] = 1 + sum of bucket weights; dis = rsqrt (deg>=1 always) ----
__global__ void k_degsum(const int* __restrict__ rowptr, const int2* __restrict__ spack,
                         float* __restrict__ dis, int N) {
    int n = blockIdx.x * blockDim.x + threadIdx.x;
    if (n < N) {
        int jb = rowptr[n], je = rowptr[n + 1];
        float s = 1.0f;  // self-loop weight
        for (int j = jb; j < je; ++j) s += __int_as_float(spack[j].y);
        dis[n] = rsqrtf(s);
    }
}

// ---- W transpose + bf16 convert (one-time, 64KB) ----
__global__ void k_wprep(const float* __restrict__ W, unsigned short* __restrict__ Wtg) {
    int n = blockIdx.x;      // 128 blocks
    int k = threadIdx.x;     // 128 threads
    Wtg[n * 128 + k] = f2bf(W[k * 128 + n]);
}

// ---- h = x @ W, bf16 MFMA 16x16x32. 64 rows x 128 cols per block, 4 waves. ----
__global__ __launch_bounds__(256) void k_gemm(const float* __restrict__ x,
                                              const unsigned short* __restrict__ Wtg,
                                              unsigned short* __restrict__ h, int N) {
    __shared__ short Xs[64][136];
    __shared__ short Ws[128][136];
    int t = threadIdx.x;
    int lane = t & 63, wid = t >> 6;
    int row0 = blockIdx.x * 64;

    {
        int r = t >> 2;
        int kseg = (t & 3) * 32;
        int gr = row0 + r;
        const float4* src = (const float4*)(x + (size_t)gr * 128 + kseg);
        #pragma unroll
        for (int i = 0; i < 4; ++i) {
            float4 v0 = make_float4(0.f, 0.f, 0.f, 0.f), v1 = v0;
            if (gr < N) { v0 = src[2 * i]; v1 = src[2 * i + 1]; }
            short8 p;
            p[0] = (short)f2bf(v0.x); p[1] = (short)f2bf(v0.y);
            p[2] = (short)f2bf(v0.z); p[3] = (short)f2bf(v0.w);
            p[4] = (short)f2bf(v1.x); p[5] = (short)f2bf(v1.y);
            p[6] = (short)f2bf(v1.z); p[7] = (short)f2bf(v1.w);
            *(short8*)&Xs[r][kseg + 8 * i] = p;
        }
    }
    {
        int n = t >> 1;
        int seg = (t & 1) * 64;
        const short* wsrc = (const short*)Wtg + n * 128 + seg;
        #pragma unroll
        for (int i = 0; i < 8; ++i)
            *(short8*)&Ws[n][seg + 8 * i] = *(const short8*)(wsrc + 8 * i);
    }
    __syncthreads();

    int q = lane >> 4;
    int m = lane & 15;
    f32x4 acc[8];
    #pragma unroll
    for (int tde = 0; tde < 8; ++tde) acc[tde] = (f32x4){0.f, 0.f, 0.f, 0.f};

    #pragma unroll
    for (int kc = 0; kc < 128; kc += 32) {
        short8 af = *(const short8*)&Xs[wid * 16 + m][kc + q * 8];
        #pragma unroll
        for (int tde = 0; tde < 8; ++tde) {
            short8 bf = *(const short8*)&Ws[tde * 16 + m][kc + q * 8];
            acc[tde] = __builtin_amdgcn_mfma_f32_16x16x32_bf16(af, bf, acc[tde], 0, 0, 0);
        }
    }

    #pragma unroll
    for (int r = 0; r < 4; ++r) {
        int grow = row0 + wid * 16 + q * 4 + r;
        if (grow < N) {
            #pragma unroll
            for (int tde = 0; tde < 8; ++tde)
                h[(size_t)grow * 128 + tde * 16 + m] = f2bf(acc[tde][r]);
        }
    }
}

// ---- gather: one wave/node, lane = 2 feature cols, unroll 4 ----
__global__ void k_gather(const unsigned int* __restrict__ hb /*bf16 pairs*/,
                         const float* __restrict__ dis, const int* __restrict__ rowptr,
                         const int2* __restrict__ spack, const float* __restrict__ bias,
                         float* __restrict__ out, int N) {
    int gid = blockIdx.x * blockDim.x + threadIdx.x;
    int node = gid >> 6;
    int lane = gid & 63;
    if (node >= N) return;
    node = __builtin_amdgcn_readfirstlane(node);

    float dn = dis[node];
    unsigned u = hb[(size_t)node * 64 + lane];
    float2 acc;
    acc.x = dn * __uint_as_float(u << 16);
    acc.y = dn * __uint_as_float(u & 0xffff0000u);

    int jb = rowptr[node], je = rowptr[node + 1];
    int j = jb;
    for (; j + 4 <= je; j += 4) {
        int2 p0 = spack[j], p1 = spack[j + 1], p2 = spack[j + 2], p3 = spack[j + 3];
        int r0 = __builtin_amdgcn_readfirstlane(p0.x);
        int r1 = __builtin_amdgcn_readfirstlane(p1.x);
        int r2 = __builtin_amdgcn_readfirstlane(p2.x);
        int r3 = __builtin_amdgcn_readfirstlane(p3.x);
        unsigned u0 = hb[(size_t)r0 * 64 + lane];
        unsigned u1 = hb[(size_t)r1 * 64 + lane];
        unsigned u2 = hb[(size_t)r2 * 64 + lane];
        unsigned u3 = hb[(size_t)r3 * 64 + lane];
        float a0 = dis[r0] * __int_as_float(p0.y);
        float a1 = dis[r1] * __int_as_float(p1.y);
        float a2 = dis[r2] * __int_as_float(p2.y);
        float a3 = dis[r3] * __int_as_float(p3.y);
        acc.x = fmaf(a0, __uint_as_float(u0 << 16), acc.x);
        acc.y = fmaf(a0, __uint_as_float(u0 & 0xffff0000u), acc.y);
        acc.x = fmaf(a1, __uint_as_float(u1 << 16), acc.x);
        acc.y = fmaf(a1, __uint_as_float(u1 & 0xffff0000u), acc.y);
        acc.x = fmaf(a2, __uint_as_float(u2 << 16), acc.x);
        acc.y = fmaf(a2, __uint_as_float(u2 & 0xffff0000u), acc.y);
        acc.x = fmaf(a3, __uint_as_float(u3 << 16), acc.x);
        acc.y = fmaf(a3, __uint_as_float(u3 & 0xffff0000u), acc.y);
    }
    for (; j < je; ++j) {
        int2 p = spack[j];
        int r = __builtin_amdgcn_readfirstlane(p.x);
        unsigned uu = hb[(size_t)r * 64 + lane];
        float a = dis[r] * __int_as_float(p.y);
        acc.x = fmaf(a, __uint_as_float(uu << 16), acc.x);
        acc.y = fmaf(a, __uint_as_float(uu & 0xffff0000u), acc.y);
    }

    int c0 = lane * 2;
    float2 bv = *(const float2*)(bias + c0);
    float2 o;
    o.x = bv.x + dn * acc.x;
    o.y = bv.y + dn * acc.y;
    *(float2*)(out + (size_t)node * 128 + c0) = o;
}

extern "C" void kernel_launch(void* const* d_in, const int* in_sizes, int n_in,
                              void* d_out, int out_size, void* d_ws, size_t ws_size,
                              hipStream_t stream) {
    const float* x     = (const float*)d_in[0];
    const int*   eidx  = (const int*)d_in[1];   // [2,E] int32
    const float* eattr = (const float*)d_in[2];
    const float* W     = (const float*)d_in[3];
    const float* bias  = (const float*)d_in[4];
    int N = in_sizes[0] / 128;
    int E = in_sizes[2];
    const int* row = eidx;
    const int* col = eidx + E;

    char* p = (char*)d_ws;
    auto carve = [&](size_t bytes) {
        char* q = p;
        p += (bytes + 255) & ~(size_t)255;
        return q;
    };
    unsigned short* h    = (unsigned short*)carve((size_t)N * 128 * sizeof(unsigned short));
    unsigned short* Wtg  = (unsigned short*)carve(128 * 128 * sizeof(unsigned short));
    float* dis    = (float*)carve((size_t)N * sizeof(float));
    int*   cnt    = (int*)carve((size_t)(N + 1) * sizeof(int));   // scanned in place -> rowptr
    unsigned short* tmp16 = (unsigned short*)carve((size_t)E * sizeof(unsigned short));
    int*   bsum   = (int*)carve(256 * sizeof(int));
    int*   boff   = (int*)carve(256 * sizeof(int));
    int2*  spack  = (int2*)carve((size_t)E * sizeof(int2));

    int M = N + 1;
    int NB = (M + ELEMS_PER_SCAN_BLOCK - 1) / ELEMS_PER_SCAN_BLOCK;

    hipMemsetAsync(cnt, 0, (size_t)M * sizeof(int), stream);
    k_pass1<<<(E + 255) / 256, 256, 0, stream>>>(col, cnt, tmp16, E);
    // scan cnt in place: k_scan1 reads cnt writes cnt (per-block excl), then add block offsets
    k_scan1<<<NB, 256, 0, stream>>>(cnt, cnt, bsum, M);
    k_scan2<<<1, 256, 0, stream>>>(bsum, boff, NB);
    k_scan3<<<NB, 256, 0, stream>>>(cnt, boff, M);
    int* rowptr = cnt;
    k_pass2<<<(E + 255) / 256, 256, 0, stream>>>(row, col, eattr, rowptr, tmp16, spack, E);
    k_degsum<<<(N + 255) / 256, 256, 0, stream>>>(rowptr, spack, dis, N);
    k_wprep<<<128, 128, 0, stream>>>(W, Wtg);
    k_gemm<<<(N + 63) / 64, 256, 0, stream>>>(x, Wtg, h, N);
    {
        size_t threads = (size_t)N * 64;
        int blocks = (int)((threads + 255) / 256);
        k_gather<<<blocks, 256, 0, stream>>>((const unsigned int*)h, dis, rowptr, spack,
                                             bias, (float*)d_out, N);
    }
}

// Round 4
// 292.468 us; speedup vs baseline: 1.9948x; 1.0746x over previous
//
#include <hip/hip_runtime.h>

// GCNConv: out = D^-1/2 (A+I) D^-1/2 X W + b
// N=100000, E=1600000, Din=Dout=128; x/W/b fp32, edge_index int32, out fp32.
//
// R3: ZERO global atomics. Two-level counting sort:
//   k_hist : per-block LDS histogram of coarse bucket col>>7 -> hist[bucket][block]
//   scan   : global exscan over (bucket,block)  -> coarse placement offsets
//   k_place: deterministic scatter via LDS cursors (scol + (row,w))
//   k_fine : 1 block / 128-node bucket: exact CSR rowptr + dis=rsqrt(1+sum w) + spack
//   gemm   : h = x@W bf16 MFMA (h stored bf16)
//   gather : 1 wave/node, 2 edges per wave-instruction (half-wave per edge,
//            uint2 loads), __shfl_xor(32) combine. 4 rows in flight.

#define ELEMS_PER_SCAN_BLOCK 2048  // 256 threads * 8
#define CHUNK 4096                 // edges per hist/place block

typedef __attribute__((ext_vector_type(8))) short short8;
typedef __attribute__((ext_vector_type(4))) float f32x4;

__device__ inline unsigned short f2bf(float f) {  // fp32 -> bf16 RNE
    unsigned u = __float_as_uint(f);
    u += 0x7fffu + ((u >> 16) & 1u);
    return (unsigned short)(u >> 16);
}
__device__ inline float bf_lo(unsigned u) { return __uint_as_float(u << 16); }
__device__ inline float bf_hi(unsigned u) { return __uint_as_float(u & 0xffff0000u); }

// ---- coarse histogram: LDS only ----
__global__ __launch_bounds__(256) void k_hist(const int* __restrict__ col,
                                              int* __restrict__ histg,
                                              int E, int NC, int NBLK) {
    __shared__ int lh[1024];
    int t = threadIdx.x, blk = blockIdx.x;
    for (int i = t; i < 1024; i += 256) lh[i] = 0;
    __syncthreads();
    int base = blk * CHUNK;
    #pragma unroll
    for (int i = 0; i < CHUNK / 256; ++i) {
        int e = base + i * 256 + t;
        if (e < E) atomicAdd(&lh[col[e] >> 7], 1);
    }
    __syncthreads();
    for (int b = t; b < NC; b += 256) histg[b * NBLK + blk] = lh[b];
}

// ---- scan (3 kernels, generic exclusive scan) ----
__device__ inline int wave_incl_scan(int x, int lane) {
    #pragma unroll
    for (int d = 1; d < 64; d <<= 1) {
        int y = __shfl_up(x, d, 64);
        if (lane >= d) x += y;
    }
    return x;
}

__global__ void k_scan1(const int* __restrict__ in, int* __restrict__ out,
                        int* __restrict__ bsum, int M) {
    __shared__ int wsum[4];
    __shared__ int woff[4];
    int t = threadIdx.x, lane = t & 63, wid = t >> 6;
    int base = blockIdx.x * ELEMS_PER_SCAN_BLOCK + t * 8;
    int v[8];
    #pragma unroll
    for (int i = 0; i < 8; ++i) v[i] = (base + i < M) ? in[base + i] : 0;
    int run = 0;
    #pragma unroll
    for (int i = 0; i < 8; ++i) { int x = v[i]; v[i] = run; run += x; }
    int incl = wave_incl_scan(run, lane);
    int excl = incl - run;
    if (lane == 63) wsum[wid] = incl;
    __syncthreads();
    if (t == 0) {
        int r = 0;
        #pragma unroll
        for (int w = 0; w < 4; ++w) { int s = wsum[w]; woff[w] = r; r += s; }
        bsum[blockIdx.x] = r;
    }
    __syncthreads();
    int off = woff[wid] + excl;
    #pragma unroll
    for (int i = 0; i < 8; ++i)
        if (base + i < M) out[base + i] = v[i] + off;
}

__global__ void k_scan2(const int* __restrict__ bsum, int* __restrict__ boff, int NB) {
    __shared__ int wsum[4];
    __shared__ int woff[4];
    int t = threadIdx.x, lane = t & 63, wid = t >> 6;
    int x = (t < NB) ? bsum[t] : 0;
    int incl = wave_incl_scan(x, lane);
    int excl = incl - x;
    if (lane == 63) wsum[wid] = incl;
    __syncthreads();
    if (t == 0) {
        int r = 0;
        #pragma unroll
        for (int w = 0; w < 4; ++w) { int s = wsum[w]; woff[w] = r; r += s; }
    }
    __syncthreads();
    if (t < NB) boff[t] = woff[wid] + excl;
}

__global__ void k_scan3(int* __restrict__ arr, const int* __restrict__ boff, int M) {
    int t = threadIdx.x;
    int base = blockIdx.x * ELEMS_PER_SCAN_BLOCK + t * 8;
    int off = boff[blockIdx.x];
    #pragma unroll
    for (int i = 0; i < 8; ++i) {
        int idx = base + i;
        if (idx < M) arr[idx] += off;
    }
}

// ---- coarse placement: LDS cursors seeded from scan; no global atomics ----
__global__ __launch_bounds__(256) void k_place(const int* __restrict__ row,
                                               const int* __restrict__ col,
                                               const float* __restrict__ wgt,
                                               const int* __restrict__ histg,
                                               int* __restrict__ scol,
                                               int2* __restrict__ srw,
                                               int E, int NC, int NBLK) {
    __shared__ int lo[1024];
    int t = threadIdx.x, blk = blockIdx.x;
    for (int b = t; b < NC; b += 256) lo[b] = histg[b * NBLK + blk];
    __syncthreads();
    int base = blk * CHUNK;
    #pragma unroll
    for (int i = 0; i < CHUNK / 256; ++i) {
        int e = base + i * 256 + t;
        if (e < E) {
            int c = col[e];
            int pos = atomicAdd(&lo[c >> 7], 1);
            scol[pos] = c;
            srw[pos] = make_int2(row[e], __float_as_int(wgt[e]));
        }
    }
}

// ---- fine pass: exact CSR within each 128-node bucket + dis ----
__global__ __launch_bounds__(256) void k_fine(const int* __restrict__ histg,
                                              const int* __restrict__ scol,
                                              const int2* __restrict__ srw,
                                              int* __restrict__ rowptr,
                                              float* __restrict__ dis,
                                              int2* __restrict__ spack,
                                              int E, int N, int NC, int NBLK) {
    __shared__ int cnt128[128];
    __shared__ float degf[128];
    __shared__ int cur128[128];
    __shared__ int wtot[2];
    int t = threadIdx.x, b = blockIdx.x;
    int nb = b << 7;
    int start = histg[b * NBLK];
    int end = (b == NC - 1) ? E : histg[(b + 1) * NBLK];
    if (t < 128) { cnt128[t] = 0; degf[t] = 1.0f; }  // 1.0 = self-loop weight
    __syncthreads();
    // phase 1: histogram + weighted degree
    for (int j = start + t; j < end; j += 256) {
        int c = scol[j] - nb;
        atomicAdd(&cnt128[c], 1);
        atomicAdd(&degf[c], __int_as_float(srw[j].y));
    }
    __syncthreads();
    // phase 2: 128-entry exclusive scan (2 waves), write rowptr/dis, seed cursors
    int v = 0, incl = 0;
    if (t < 128) {
        v = cnt128[t];
        incl = wave_incl_scan(v, t & 63);
        if ((t & 63) == 63) wtot[t >> 6] = incl;
    }
    __syncthreads();
    if (t < 128) {
        int excl = incl - v + ((t >= 64) ? wtot[0] : 0);
        int p = start + excl;
        cur128[t] = p;
        int n = nb + t;
        if (n < N) {
            rowptr[n] = p;
            dis[n] = rsqrtf(degf[t]);
        }
    }
    if (t == 0 && b == NC - 1) rowptr[N] = E;
    __syncthreads();
    // phase 3: final placement
    for (int j = start + t; j < end; j += 256) {
        int c = scol[j] - nb;
        int pos = atomicAdd(&cur128[c], 1);
        spack[pos] = srw[j];
    }
}

// ---- W transpose + bf16 convert ----
__global__ void k_wprep(const float* __restrict__ W, unsigned short* __restrict__ Wtg) {
    int n = blockIdx.x;
    int k = threadIdx.x;
    Wtg[n * 128 + k] = f2bf(W[k * 128 + n]);
}

// ---- h = x @ W, bf16 MFMA 16x16x32. 64 rows x 128 cols / block, 4 waves. ----
__global__ __launch_bounds__(256) void k_gemm(const float* __restrict__ x,
                                              const unsigned short* __restrict__ Wtg,
                                              unsigned short* __restrict__ h, int N) {
    __shared__ short Xs[64][136];
    __shared__ short Ws[128][136];
    int t = threadIdx.x;
    int lane = t & 63, wid = t >> 6;
    int row0 = blockIdx.x * 64;
    {
        int r = t >> 2;
        int kseg = (t & 3) * 32;
        int gr = row0 + r;
        const float4* src = (const float4*)(x + (size_t)gr * 128 + kseg);
        #pragma unroll
        for (int i = 0; i < 4; ++i) {
            float4 v0 = make_float4(0.f, 0.f, 0.f, 0.f), v1 = v0;
            if (gr < N) { v0 = src[2 * i]; v1 = src[2 * i + 1]; }
            short8 p;
            p[0] = (short)f2bf(v0.x); p[1] = (short)f2bf(v0.y);
            p[2] = (short)f2bf(v0.z); p[3] = (short)f2bf(v0.w);
            p[4] = (short)f2bf(v1.x); p[5] = (short)f2bf(v1.y);
            p[6] = (short)f2bf(v1.z); p[7] = (short)f2bf(v1.w);
            *(short8*)&Xs[r][kseg + 8 * i] = p;
        }
    }
    {
        int n = t >> 1;
        int seg = (t & 1) * 64;
        const short* wsrc = (const short*)Wtg + n * 128 + seg;
        #pragma unroll
        for (int i = 0; i < 8; ++i)
            *(short8*)&Ws[n][seg + 8 * i] = *(const short8*)(wsrc + 8 * i);
    }
    __syncthreads();

    int q = lane >> 4;
    int m = lane & 15;
    f32x4 acc[8];
    #pragma unroll
    for (int tde = 0; tde < 8; ++tde) acc[tde] = (f32x4){0.f, 0.f, 0.f, 0.f};
    #pragma unroll
    for (int kc = 0; kc < 128; kc += 32) {
        short8 af = *(const short8*)&Xs[wid * 16 + m][kc + q * 8];
        #pragma unroll
        for (int tde = 0; tde < 8; ++tde) {
            short8 bf = *(const short8*)&Ws[tde * 16 + m][kc + q * 8];
            acc[tde] = __builtin_amdgcn_mfma_f32_16x16x32_bf16(af, bf, acc[tde], 0, 0, 0);
        }
    }
    #pragma unroll
    for (int r = 0; r < 4; ++r) {
        int grow = row0 + wid * 16 + q * 4 + r;
        if (grow < N) {
            #pragma unroll
            for (int tde = 0; tde < 8; ++tde)
                h[(size_t)grow * 128 + tde * 16 + m] = f2bf(acc[tde][r]);
        }
    }
}

// ---- gather v2: 1 wave/node, half-wave per edge (2 edges per instruction) ----
__global__ __launch_bounds__(256) void k_gather(const uint2* __restrict__ hb2,
                                                const float* __restrict__ dis,
                                                const int* __restrict__ rowptr,
                                                const int2* __restrict__ spack,
                                                const float* __restrict__ bias,
                                                float* __restrict__ out, int N) {
    int gid = blockIdx.x * blockDim.x + threadIdx.x;
    int node = gid >> 6;
    int lane = gid & 63;
    if (node >= N) return;
    node = __builtin_amdgcn_readfirstlane(node);
    int half = lane >> 5, sub = lane & 31;  // sub covers cols [4*sub, 4*sub+4)

    float dn = dis[node];
    float4 acc = make_float4(0.f, 0.f, 0.f, 0.f);
    {   // self term: half0 only (half1 would double-count after shfl combine)
        uint2 us = hb2[(size_t)node * 32 + sub];
        float s = (half == 0) ? dn : 0.0f;
        acc.x = s * bf_lo(us.x); acc.y = s * bf_hi(us.x);
        acc.z = s * bf_lo(us.y); acc.w = s * bf_hi(us.y);
    }
    int jb = rowptr[node], je = rowptr[node + 1];
    int j = jb;
    for (; j + 8 <= je; j += 8) {   // 8 edges per iter; 4 rows in flight
        int2 p0 = spack[j + half];
        int2 p1 = spack[j + 2 + half];
        int2 p2 = spack[j + 4 + half];
        int2 p3 = spack[j + 6 + half];
        uint2 h0 = hb2[(size_t)p0.x * 32 + sub];
        uint2 h1 = hb2[(size_t)p1.x * 32 + sub];
        uint2 h2 = hb2[(size_t)p2.x * 32 + sub];
        uint2 h3 = hb2[(size_t)p3.x * 32 + sub];
        float a0 = dis[p0.x] * __int_as_float(p0.y);
        float a1 = dis[p1.x] * __int_as_float(p1.y);
        float a2 = dis[p2.x] * __int_as_float(p2.y);
        float a3 = dis[p3.x] * __int_as_float(p3.y);
        acc.x = fmaf(a0, bf_lo(h0.x), acc.x); acc.y = fmaf(a0, bf_hi(h0.x), acc.y);
        acc.z = fmaf(a0, bf_lo(h0.y), acc.z); acc.w = fmaf(a0, bf_hi(h0.y), acc.w);
        acc.x = fmaf(a1, bf_lo(h1.x), acc.x); acc.y = fmaf(a1, bf_hi(h1.x), acc.y);
        acc.z = fmaf(a1, bf_lo(h1.y), acc.z); acc.w = fmaf(a1, bf_hi(h1.y), acc.w);
        acc.x = fmaf(a2, bf_lo(h2.x), acc.x); acc.y = fmaf(a2, bf_hi(h2.x), acc.y);
        acc.z = fmaf(a2, bf_lo(h2.y), acc.z); acc.w = fmaf(a2, bf_hi(h2.y), acc.w);
        acc.x = fmaf(a3, bf_lo(h3.x), acc.x); acc.y = fmaf(a3, bf_hi(h3.x), acc.y);
        acc.z = fmaf(a3, bf_lo(h3.y), acc.z); acc.w = fmaf(a3, bf_hi(h3.y), acc.w);
    }
    for (; j < je; j += 2) {   // remainder, predicated per half
        int e = j + half;
        bool act = e < je;
        int2 p = act ? spack[e] : make_int2(0, 0);
        uint2 hh = hb2[(size_t)(act ? p.x : 0) * 32 + sub];
        float a = act ? dis[p.x] * __int_as_float(p.y) : 0.0f;
        acc.x = fmaf(a, bf_lo(hh.x), acc.x); acc.y = fmaf(a, bf_hi(hh.x), acc.y);
        acc.z = fmaf(a, bf_lo(hh.y), acc.z); acc.w = fmaf(a, bf_hi(hh.y), acc.w);
    }
    // combine halves
    acc.x += __shfl_xor(acc.x, 32);
    acc.y += __shfl_xor(acc.y, 32);
    acc.z += __shfl_xor(acc.z, 32);
    acc.w += __shfl_xor(acc.w, 32);
    if (half == 0) {
        float4 bv = ((const float4*)bias)[sub];
        float4 o = make_float4(bv.x + dn * acc.x, bv.y + dn * acc.y,
                               bv.z + dn * acc.z, bv.w + dn * acc.w);
        ((float4*)(out + (size_t)node * 128))[sub] = o;
    }
}

extern "C" void kernel_launch(void* const* d_in, const int* in_sizes, int n_in,
                              void* d_out, int out_size, void* d_ws, size_t ws_size,
                              hipStream_t stream) {
    const float* x     = (const float*)d_in[0];
    const int*   eidx  = (const int*)d_in[1];   // [2,E] int32
    const float* eattr = (const float*)d_in[2];
    const float* W     = (const float*)d_in[3];
    const float* bias  = (const float*)d_in[4];
    int N = in_sizes[0] / 128;
    int E = in_sizes[2];
    const int* row = eidx;
    const int* col = eidx + E;

    int NC = (N + 127) >> 7;                       // 782 coarse buckets
    int NBLK = (E + CHUNK - 1) / CHUNK;            // 391 hist/place blocks

    char* p = (char*)d_ws;
    auto carve = [&](size_t bytes) {
        char* q = p;
        p += (bytes + 255) & ~(size_t)255;
        return q;
    };
    unsigned short* h   = (unsigned short*)carve((size_t)N * 128 * sizeof(unsigned short));
    unsigned short* Wtg = (unsigned short*)carve(128 * 128 * sizeof(unsigned short));
    float* dis    = (float*)carve((size_t)N * sizeof(float));
    int*   rowptr = (int*)carve((size_t)(N + 1) * sizeof(int));
    int*   histg  = (int*)carve((size_t)NC * NBLK * sizeof(int));
    int*   scol   = (int*)carve((size_t)E * sizeof(int));
    int2*  srw    = (int2*)carve((size_t)E * sizeof(int2));
    int2*  spack  = (int2*)carve((size_t)E * sizeof(int2));
    int*   bsum   = (int*)carve(256 * sizeof(int));
    int*   boff   = (int*)carve(256 * sizeof(int));

    int M = NC * NBLK;                              // 305,762
    int NBs = (M + ELEMS_PER_SCAN_BLOCK - 1) / ELEMS_PER_SCAN_BLOCK;  // 150

    k_hist<<<NBLK, 256, 0, stream>>>(col, histg, E, NC, NBLK);
    k_scan1<<<NBs, 256, 0, stream>>>(histg, histg, bsum, M);
    k_scan2<<<1, 256, 0, stream>>>(bsum, boff, NBs);
    k_scan3<<<NBs, 256, 0, stream>>>(histg, boff, M);
    k_place<<<NBLK, 256, 0, stream>>>(row, col, eattr, histg, scol, srw, E, NC, NBLK);
    k_fine<<<NC, 256, 0, stream>>>(histg, scol, srw, rowptr, dis, spack, E, N, NC, NBLK);
    k_wprep<<<128, 128, 0, stream>>>(W, Wtg);
    k_gemm<<<(N + 63) / 64, 256, 0, stream>>>(x, Wtg, h, N);
    {
        size_t threads = (size_t)N * 64;
        int blocks = (int)((threads + 255) / 256);
        k_gather<<<blocks, 256, 0, stream>>>((const uint2*)h, dis, rowptr, spack,
                                             bias, (float*)d_out, N);
    }
}

// Round 5
// 277.090 us; speedup vs baseline: 2.1056x; 1.0555x over previous
//
#include <hip/hip_runtime.h>

// GCNConv: out = D^-1/2 (A+I) D^-1/2 X W + b
// N=100000, E=1600000, Din=Dout=128; x/W/b fp32, edge_index int32, out fp32.
//
// R4: zero global atomics (two-level counting sort), packed sort payload
//     ((c&127)<<17 | row, w) -> no scol array, gather v1 structure with
//     unroll-8 (8 h-rows in flight) + nontemporal out/spack.

#define ELEMS_PER_SCAN_BLOCK 2048  // 256 threads * 8
#define CHUNK 4096                 // edges per hist/place block

typedef __attribute__((ext_vector_type(8))) short short8;
typedef __attribute__((ext_vector_type(4))) float f32x4;

__device__ inline unsigned short f2bf(float f) {  // fp32 -> bf16 RNE
    unsigned u = __float_as_uint(f);
    u += 0x7fffu + ((u >> 16) & 1u);
    return (unsigned short)(u >> 16);
}
__device__ inline float bf_lo(unsigned u) { return __uint_as_float(u << 16); }
__device__ inline float bf_hi(unsigned u) { return __uint_as_float(u & 0xffff0000u); }

// ---- coarse histogram: LDS only ----
__global__ __launch_bounds__(256) void k_hist(const int* __restrict__ col,
                                              int* __restrict__ histg,
                                              int E, int NC, int NBLK) {
    __shared__ int lh[1024];
    int t = threadIdx.x, blk = blockIdx.x;
    for (int i = t; i < 1024; i += 256) lh[i] = 0;
    __syncthreads();
    int base = blk * CHUNK;
    #pragma unroll
    for (int i = 0; i < CHUNK / 256; ++i) {
        int e = base + i * 256 + t;
        if (e < E) atomicAdd(&lh[col[e] >> 7], 1);
    }
    __syncthreads();
    for (int b = t; b < NC; b += 256) histg[b * NBLK + blk] = lh[b];
}

// ---- scan (3 kernels) ----
__device__ inline int wave_incl_scan(int x, int lane) {
    #pragma unroll
    for (int d = 1; d < 64; d <<= 1) {
        int y = __shfl_up(x, d, 64);
        if (lane >= d) x += y;
    }
    return x;
}

__global__ void k_scan1(const int* __restrict__ in, int* __restrict__ out,
                        int* __restrict__ bsum, int M) {
    __shared__ int wsum[4];
    __shared__ int woff[4];
    int t = threadIdx.x, lane = t & 63, wid = t >> 6;
    int base = blockIdx.x * ELEMS_PER_SCAN_BLOCK + t * 8;
    int v[8];
    #pragma unroll
    for (int i = 0; i < 8; ++i) v[i] = (base + i < M) ? in[base + i] : 0;
    int run = 0;
    #pragma unroll
    for (int i = 0; i < 8; ++i) { int x = v[i]; v[i] = run; run += x; }
    int incl = wave_incl_scan(run, lane);
    int excl = incl - run;
    if (lane == 63) wsum[wid] = incl;
    __syncthreads();
    if (t == 0) {
        int r = 0;
        #pragma unroll
        for (int w = 0; w < 4; ++w) { int s = wsum[w]; woff[w] = r; r += s; }
        bsum[blockIdx.x] = r;
    }
    __syncthreads();
    int off = woff[wid] + excl;
    #pragma unroll
    for (int i = 0; i < 8; ++i)
        if (base + i < M) out[base + i] = v[i] + off;
}

__global__ void k_scan2(const int* __restrict__ bsum, int* __restrict__ boff, int NB) {
    __shared__ int wsum[4];
    __shared__ int woff[4];
    int t = threadIdx.x, lane = t & 63, wid = t >> 6;
    int x = (t < NB) ? bsum[t] : 0;
    int incl = wave_incl_scan(x, lane);
    int excl = incl - x;
    if (lane == 63) wsum[wid] = incl;
    __syncthreads();
    if (t == 0) {
        int r = 0;
        #pragma unroll
        for (int w = 0; w < 4; ++w) { int s = wsum[w]; woff[w] = r; r += s; }
    }
    __syncthreads();
    if (t < NB) boff[t] = woff[wid] + excl;
}

__global__ void k_scan3(int* __restrict__ arr, const int* __restrict__ boff, int M) {
    int t = threadIdx.x;
    int base = blockIdx.x * ELEMS_PER_SCAN_BLOCK + t * 8;
    int off = boff[blockIdx.x];
    #pragma unroll
    for (int i = 0; i < 8; ++i) {
        int idx = base + i;
        if (idx < M) arr[idx] += off;
    }
}

// ---- coarse placement: LDS cursors; payload ((c&127)<<17|row, w) ----
__global__ __launch_bounds__(256) void k_place(const int* __restrict__ row,
                                               const int* __restrict__ col,
                                               const float* __restrict__ wgt,
                                               const int* __restrict__ histg,
                                               int2* __restrict__ srw,
                                               int E, int NC, int NBLK) {
    __shared__ int lo[1024];
    int t = threadIdx.x, blk = blockIdx.x;
    for (int b = t; b < NC; b += 256) lo[b] = histg[b * NBLK + blk];
    __syncthreads();
    int base = blk * CHUNK;
    #pragma unroll
    for (int i = 0; i < CHUNK / 256; ++i) {
        int e = base + i * 256 + t;
        if (e < E) {
            int c = col[e];
            int pos = atomicAdd(&lo[c >> 7], 1);
            srw[pos] = make_int2(((c & 127) << 17) | row[e], __float_as_int(wgt[e]));
        }
    }
}

// ---- fine pass: exact CSR within each 128-node bucket + dis + spack ----
__global__ __launch_bounds__(256) void k_fine(const int* __restrict__ histg,
                                              const int2* __restrict__ srw,
                                              int* __restrict__ rowptr,
                                              float* __restrict__ dis,
                                              int2* __restrict__ spack,
                                              int E, int N, int NC, int NBLK) {
    __shared__ int cnt128[128];
    __shared__ float degf[128];
    __shared__ int cur128[128];
    __shared__ int wtot[2];
    int t = threadIdx.x, b = blockIdx.x;
    int nb = b << 7;
    int start = histg[b * NBLK];
    int end = (b == NC - 1) ? E : histg[(b + 1) * NBLK];
    if (t < 128) { cnt128[t] = 0; degf[t] = 1.0f; }  // 1.0 = self-loop weight
    __syncthreads();
    // phase 1: histogram + weighted degree
    for (int j = start + t; j < end; j += 256) {
        int2 s = srw[j];
        int c = s.x >> 17;
        atomicAdd(&cnt128[c], 1);
        atomicAdd(&degf[c], __int_as_float(s.y));
    }
    __syncthreads();
    // phase 2: 128-entry exclusive scan, write rowptr/dis, seed cursors
    int v = 0, incl = 0;
    if (t < 128) {
        v = cnt128[t];
        incl = wave_incl_scan(v, t & 63);
        if ((t & 63) == 63) wtot[t >> 6] = incl;
    }
    __syncthreads();
    if (t < 128) {
        int excl = incl - v + ((t >= 64) ? wtot[0] : 0);
        int p = start + excl;
        cur128[t] = p;
        int n = nb + t;
        if (n < N) {
            rowptr[n] = p;
            dis[n] = rsqrtf(degf[t]);
        }
    }
    if (t == 0 && b == NC - 1) rowptr[N] = E;
    __syncthreads();
    // phase 3: final placement (strip c bits -> (row, w))
    for (int j = start + t; j < end; j += 256) {
        int2 s = srw[j];
        int c = s.x >> 17;
        int pos = atomicAdd(&cur128[c], 1);
        spack[pos] = make_int2(s.x & 0x1FFFF, s.y);
    }
}

// ---- W transpose + bf16 convert ----
__global__ void k_wprep(const float* __restrict__ W, unsigned short* __restrict__ Wtg) {
    int n = blockIdx.x;
    int k = threadIdx.x;
    Wtg[n * 128 + k] = f2bf(W[k * 128 + n]);
}

// ---- h = x @ W, bf16 MFMA 16x16x32. 64 rows x 128 cols / block, 4 waves. ----
__global__ __launch_bounds__(256) void k_gemm(const float* __restrict__ x,
                                              const unsigned short* __restrict__ Wtg,
                                              unsigned short* __restrict__ h, int N) {
    __shared__ short Xs[64][136];
    __shared__ short Ws[128][136];
    int t = threadIdx.x;
    int lane = t & 63, wid = t >> 6;
    int row0 = blockIdx.x * 64;
    {
        int r = t >> 2;
        int kseg = (t & 3) * 32;
        int gr = row0 + r;
        const float4* src = (const float4*)(x + (size_t)gr * 128 + kseg);
        #pragma unroll
        for (int i = 0; i < 4; ++i) {
            float4 v0 = make_float4(0.f, 0.f, 0.f, 0.f), v1 = v0;
            if (gr < N) { v0 = src[2 * i]; v1 = src[2 * i + 1]; }
            short8 p;
            p[0] = (short)f2bf(v0.x); p[1] = (short)f2bf(v0.y);
            p[2] = (short)f2bf(v0.z); p[3] = (short)f2bf(v0.w);
            p[4] = (short)f2bf(v1.x); p[5] = (short)f2bf(v1.y);
            p[6] = (short)f2bf(v1.z); p[7] = (short)f2bf(v1.w);
            *(short8*)&Xs[r][kseg + 8 * i] = p;
        }
    }
    {
        int n = t >> 1;
        int seg = (t & 1) * 64;
        const short* wsrc = (const short*)Wtg + n * 128 + seg;
        #pragma unroll
        for (int i = 0; i < 8; ++i)
            *(short8*)&Ws[n][seg + 8 * i] = *(const short8*)(wsrc + 8 * i);
    }
    __syncthreads();

    int q = lane >> 4;
    int m = lane & 15;
    f32x4 acc[8];
    #pragma unroll
    for (int tde = 0; tde < 8; ++tde) acc[tde] = (f32x4){0.f, 0.f, 0.f, 0.f};
    #pragma unroll
    for (int kc = 0; kc < 128; kc += 32) {
        short8 af = *(const short8*)&Xs[wid * 16 + m][kc + q * 8];
        #pragma unroll
        for (int tde = 0; tde < 8; ++tde) {
            short8 bf = *(const short8*)&Ws[tde * 16 + m][kc + q * 8];
            acc[tde] = __builtin_amdgcn_mfma_f32_16x16x32_bf16(af, bf, acc[tde], 0, 0, 0);
        }
    }
    #pragma unroll
    for (int r = 0; r < 4; ++r) {
        int grow = row0 + wid * 16 + q * 4 + r;
        if (grow < N) {
            #pragma unroll
            for (int tde = 0; tde < 8; ++tde)
                h[(size_t)grow * 128 + tde * 16 + m] = f2bf(acc[tde][r]);
        }
    }
}

// ---- gather v3: 1 wave/node, full wave per edge, unroll 8, nt out ----
__global__ __launch_bounds__(256) void k_gather(const unsigned int* __restrict__ hb,
                                                const float* __restrict__ dis,
                                                const int* __restrict__ rowptr,
                                                const long* __restrict__ spackl,
                                                const float* __restrict__ bias,
                                                float* __restrict__ out, int N) {
    int gid = blockIdx.x * blockDim.x + threadIdx.x;
    int node = gid >> 6;
    int lane = gid & 63;
    if (node >= N) return;
    node = __builtin_amdgcn_readfirstlane(node);

    float dn = dis[node];
    unsigned u = hb[(size_t)node * 64 + lane];
    float2 acc;
    acc.x = dn * bf_lo(u);
    acc.y = dn * bf_hi(u);

    int jb = rowptr[node], je = rowptr[node + 1];
    int j = jb;
    for (; j + 8 <= je; j += 8) {   // 8 h-rows in flight
        long q0 = __builtin_nontemporal_load(spackl + j);
        long q1 = __builtin_nontemporal_load(spackl + j + 1);
        long q2 = __builtin_nontemporal_load(spackl + j + 2);
        long q3 = __builtin_nontemporal_load(spackl + j + 3);
        long q4 = __builtin_nontemporal_load(spackl + j + 4);
        long q5 = __builtin_nontemporal_load(spackl + j + 5);
        long q6 = __builtin_nontemporal_load(spackl + j + 6);
        long q7 = __builtin_nontemporal_load(spackl + j + 7);
        int r0 = __builtin_amdgcn_readfirstlane((int)q0);
        int r1 = __builtin_amdgcn_readfirstlane((int)q1);
        int r2 = __builtin_amdgcn_readfirstlane((int)q2);
        int r3 = __builtin_amdgcn_readfirstlane((int)q3);
        int r4 = __builtin_amdgcn_readfirstlane((int)q4);
        int r5 = __builtin_amdgcn_readfirstlane((int)q5);
        int r6 = __builtin_amdgcn_readfirstlane((int)q6);
        int r7 = __builtin_amdgcn_readfirstlane((int)q7);
        unsigned u0 = hb[(size_t)r0 * 64 + lane];
        unsigned u1 = hb[(size_t)r1 * 64 + lane];
        unsigned u2 = hb[(size_t)r2 * 64 + lane];
        unsigned u3 = hb[(size_t)r3 * 64 + lane];
        unsigned u4 = hb[(size_t)r4 * 64 + lane];
        unsigned u5 = hb[(size_t)r5 * 64 + lane];
        unsigned u6 = hb[(size_t)r6 * 64 + lane];
        unsigned u7 = hb[(size_t)r7 * 64 + lane];
        float a0 = dis[r0] * __uint_as_float((unsigned)(q0 >> 32));
        float a1 = dis[r1] * __uint_as_float((unsigned)(q1 >> 32));
        float a2 = dis[r2] * __uint_as_float((unsigned)(q2 >> 32));
        float a3 = dis[r3] * __uint_as_float((unsigned)(q3 >> 32));
        float a4 = dis[r4] * __uint_as_float((unsigned)(q4 >> 32));
        float a5 = dis[r5] * __uint_as_float((unsigned)(q5 >> 32));
        float a6 = dis[r6] * __uint_as_float((unsigned)(q6 >> 32));
        float a7 = dis[r7] * __uint_as_float((unsigned)(q7 >> 32));
        acc.x = fmaf(a0, bf_lo(u0), acc.x); acc.y = fmaf(a0, bf_hi(u0), acc.y);
        acc.x = fmaf(a1, bf_lo(u1), acc.x); acc.y = fmaf(a1, bf_hi(u1), acc.y);
        acc.x = fmaf(a2, bf_lo(u2), acc.x); acc.y = fmaf(a2, bf_hi(u2), acc.y);
        acc.x = fmaf(a3, bf_lo(u3), acc.x); acc.y = fmaf(a3, bf_hi(u3), acc.y);
        acc.x = fmaf(a4, bf_lo(u4), acc.x); acc.y = fmaf(a4, bf_hi(u4), acc.y);
        acc.x = fmaf(a5, bf_lo(u5), acc.x); acc.y = fmaf(a5, bf_hi(u5), acc.y);
        acc.x = fmaf(a6, bf_lo(u6), acc.x); acc.y = fmaf(a6, bf_hi(u6), acc.y);
        acc.x = fmaf(a7, bf_lo(u7), acc.x); acc.y = fmaf(a7, bf_hi(u7), acc.y);
    }
    for (; j < je; ++j) {
        long q = __builtin_nontemporal_load(spackl + j);
        int r = __builtin_amdgcn_readfirstlane((int)q);
        unsigned uu = hb[(size_t)r * 64 + lane];
        float a = dis[r] * __uint_as_float((unsigned)(q >> 32));
        acc.x = fmaf(a, bf_lo(uu), acc.x);
        acc.y = fmaf(a, bf_hi(uu), acc.y);
    }

    int c0 = lane * 2;
    float2 bv = *(const float2*)(bias + c0);
    float2 o;
    o.x = bv.x + dn * acc.x;
    o.y = bv.y + dn * acc.y;
    union { float2 f; double d; } cvt;
    cvt.f = o;
    __builtin_nontemporal_store(cvt.d, (double*)(out + (size_t)node * 128 + c0));
}

extern "C" void kernel_launch(void* const* d_in, const int* in_sizes, int n_in,
                              void* d_out, int out_size, void* d_ws, size_t ws_size,
                              hipStream_t stream) {
    const float* x     = (const float*)d_in[0];
    const int*   eidx  = (const int*)d_in[1];   // [2,E] int32
    const float* eattr = (const float*)d_in[2];
    const float* W     = (const float*)d_in[3];
    const float* bias  = (const float*)d_in[4];
    int N = in_sizes[0] / 128;
    int E = in_sizes[2];
    const int* row = eidx;
    const int* col = eidx + E;

    int NC = (N + 127) >> 7;                       // 782 coarse buckets
    int NBLK = (E + CHUNK - 1) / CHUNK;            // 391 hist/place blocks

    char* p = (char*)d_ws;
    auto carve = [&](size_t bytes) {
        char* q = p;
        p += (bytes + 255) & ~(size_t)255;
        return q;
    };
    unsigned short* h   = (unsigned short*)carve((size_t)N * 128 * sizeof(unsigned short));
    unsigned short* Wtg = (unsigned short*)carve(128 * 128 * sizeof(unsigned short));
    float* dis    = (float*)carve((size_t)N * sizeof(float));
    int*   rowptr = (int*)carve((size_t)(N + 1) * sizeof(int));
    int*   histg  = (int*)carve((size_t)NC * NBLK * sizeof(int));
    int2*  srw    = (int2*)carve((size_t)E * sizeof(int2));
    int2*  spack  = (int2*)carve((size_t)E * sizeof(int2));
    int*   bsum   = (int*)carve(256 * sizeof(int));
    int*   boff   = (int*)carve(256 * sizeof(int));

    int M = NC * NBLK;
    int NBs = (M + ELEMS_PER_SCAN_BLOCK - 1) / ELEMS_PER_SCAN_BLOCK;

    k_hist<<<NBLK, 256, 0, stream>>>(col, histg, E, NC, NBLK);
    k_scan1<<<NBs, 256, 0, stream>>>(histg, histg, bsum, M);
    k_scan2<<<1, 256, 0, stream>>>(bsum, boff, NBs);
    k_scan3<<<NBs, 256, 0, stream>>>(histg, boff, M);
    k_place<<<NBLK, 256, 0, stream>>>(row, col, eattr, histg, srw, E, NC, NBLK);
    k_fine<<<NC, 256, 0, stream>>>(histg, srw, rowptr, dis, spack, E, N, NC, NBLK);
    k_wprep<<<128, 128, 0, stream>>>(W, Wtg);
    k_gemm<<<(N + 63) / 64, 256, 0, stream>>>(x, Wtg, h, N);
    {
        size_t threads = (size_t)N * 64;
        int blocks = (int)((threads + 255) / 256);
        k_gather<<<blocks, 256, 0, stream>>>((const unsigned int*)h, dis, rowptr,
                                             (const long*)spack, bias, (float*)d_out, N);
    }
}